// Round 6
// baseline (346.698 us; speedup 1.0000x reference)
//
#include <hip/hip_runtime.h>
#include <math.h>

typedef __attribute__((ext_vector_type(8))) short short8;
typedef __attribute__((ext_vector_type(4))) float f32x4;
typedef unsigned short u16;

__device__ __forceinline__ float b2f(u16 u) {
    union { unsigned u; float f; } c; c.u = ((unsigned)u) << 16; return c.f;
}
__device__ __forceinline__ u16 f2b(float f) {
    unsigned u = __float_as_uint(f);
    u += 0x7fffu + ((u >> 16) & 1u);   // RNE
    return (u16)(u >> 16);
}

__device__ __forceinline__ void gl_lds16(const u16* g, u16* l) {
    __builtin_amdgcn_global_load_lds(
        (const __attribute__((address_space(1))) void*)g,
        (__attribute__((address_space(3))) void*)l,
        16, 0, 0);
}

// fp32 -> bf16 (RNE), n multiple of 8, one thread per 8 elements
__global__ __launch_bounds__(256) void cvt_f32_bf16(const float* __restrict__ src,
                                                    u16* __restrict__ dst, int n) {
    const int i = (blockIdx.x * 256 + threadIdx.x) * 8;
    if (i >= n) return;
    const float4 a = *(const float4*)&src[i];
    const float4 b = *(const float4*)&src[i + 4];
    short8 o;
    o[0] = (short)f2b(a.x); o[1] = (short)f2b(a.y);
    o[2] = (short)f2b(a.z); o[3] = (short)f2b(a.w);
    o[4] = (short)f2b(b.x); o[5] = (short)f2b(b.y);
    o[6] = (short)f2b(b.z); o[7] = (short)f2b(b.w);
    *(short8*)&dst[i] = o;
}

// 4 weight matrices (1M fp32 each) -> contiguous bf16; z selects source
__global__ __launch_bounds__(256) void cvt_weights(
    const float* __restrict__ w0, const float* __restrict__ w1,
    const float* __restrict__ w2, const float* __restrict__ w3,
    u16* __restrict__ dst) {
    const int z = blockIdx.z;
    const float* src = (z == 0) ? w0 : (z == 1) ? w1 : (z == 2) ? w2 : w3;
    const int i = (blockIdx.x * 256 + threadIdx.x) * 8;
    const float4 a = *(const float4*)&src[i];
    const float4 b = *(const float4*)&src[i + 4];
    short8 o;
    o[0] = (short)f2b(a.x); o[1] = (short)f2b(a.y);
    o[2] = (short)f2b(a.z); o[3] = (short)f2b(a.w);
    o[4] = (short)f2b(b.x); o[5] = (short)f2b(b.y);
    o[6] = (short)f2b(b.z); o[7] = (short)f2b(b.w);
    *(short8*)&dst[(long)z * 1024 * 1024 + i] = o;
}

// Shared GEMM body: C[M,N] = scale * A[M,K] @ W[N,K]^T  (bf16 in, fp32 accum)
// Block tile (AM*32) x 128; 4 waves, each computing (AM*16) x 64.
// AM=8 -> 256x128 block tile (barrier-drain amortization: 2x MFMA per K-step,
// 25% less LDS traffic per MFMA). AM=4 -> original 128x128.
// XOR-swizzled LDS (0 bank conflicts, verified R4); loop-carried pointers (R5).
template<int AM, typename OT>
__device__ __forceinline__ void gemm_body(
    const u16* __restrict__ A, const u16* __restrict__ W, OT* __restrict__ C,
    int lda, int ldw, int ldc, int K, float scale)
{
    __shared__ u16 lsA[AM * 32 * 32];   // (AM*32) rows x 32 cols
    __shared__ u16 lsB[128 * 32];

    const int m0 = blockIdx.y * (AM * 32);
    const int n0 = blockIdx.x * 128;
    const int t = threadIdx.x;
    const int lane = t & 63;
    const int wave = t >> 6;
    const int wm = (wave & 1) * (AM * 16);
    const int wn = (wave >> 1) * 64;

    // staging: thread t covers row sr of each 64-row chunk; col-group
    // XOR-swizzled by (row>>1)&3 == (t>>3)&3 (row-chunk-invariant).
    const int sr = t >> 2;
    const int scol = ((t & 3) ^ ((t >> 3) & 3)) * 8;

    // loop-carried global pointers (advance 32 elems = 64 B per K-step)
    const u16* pa[AM / 2];
#pragma unroll
    for (int i = 0; i < AM / 2; ++i)
        pa[i] = A + (long)(m0 + i * 64 + sr) * lda + scol;
    const u16* pw0 = W + (long)(n0 + sr) * ldw + scol;
    const u16* pw1 = pw0 + (long)64 * ldw;

    f32x4 acc[AM][4];
#pragma unroll
    for (int i = 0; i < AM; ++i)
#pragma unroll
        for (int j = 0; j < 4; ++j)
            acc[i][j] = (f32x4){0.f, 0.f, 0.f, 0.f};

    const int fr = lane & 15;   // fragment row (m / n)
    const int fq = lane >> 4;   // quad
    const int swz = (fq ^ ((fr >> 1) & 3)) * 8;
    const int aoff = (wm + fr) * 32 + swz;
    const int boff = (wn + fr) * 32 + swz;

    for (int k0 = 0; k0 < K; k0 += 32) {
        __syncthreads();  // protect LDS against previous iteration's readers
#pragma unroll
        for (int i = 0; i < AM / 2; ++i) {
            gl_lds16(pa[i], &lsA[i * 2048 + t * 8]);
            pa[i] += 32;
        }
        gl_lds16(pw0, &lsB[t * 8]);        pw0 += 32;
        gl_lds16(pw1, &lsB[2048 + t * 8]); pw1 += 32;
        __syncthreads();  // drains vmcnt (global_load_lds) before consuming LDS

        short8 af[AM], bf[4];
#pragma unroll
        for (int i = 0; i < AM; ++i)
            af[i] = *(const short8*)&lsA[aoff + i * 512];   // 16 rows * 32 elems
#pragma unroll
        for (int j = 0; j < 4; ++j)
            bf[j] = *(const short8*)&lsB[boff + j * 512];
#pragma unroll
        for (int i = 0; i < AM; ++i)
#pragma unroll
            for (int j = 0; j < 4; ++j)
                acc[i][j] = __builtin_amdgcn_mfma_f32_16x16x32_bf16(af[i], bf[j], acc[i][j], 0, 0, 0);
    }

    // C/D layout: col = lane&15, row = quad*4 + reg  [verified m89/m91]
#pragma unroll
    for (int i = 0; i < AM; ++i) {
#pragma unroll
        for (int j = 0; j < 4; ++j) {
            const int row0 = m0 + wm + i * 16 + fq * 4;
            const int col = n0 + wn + j * 16 + fr;
#pragma unroll
            for (int r = 0; r < 4; ++r) {
                const int row = row0 + r;
                const float val = acc[i][j][r] * scale;
                if (sizeof(OT) == 2) {
                    ((u16*)C)[(long)row * ldc + col] = f2b(val);
                } else {
                    ((float*)C)[(long)row * ldc + col] = val;
                }
            }
        }
    }
}

// generic z-strided GEMM
template<int AM, typename OT>
__global__ __launch_bounds__(256, 2) void gemm_bt(
    const u16* __restrict__ A, const u16* __restrict__ W, OT* __restrict__ C,
    int lda, int ldw, int ldc, int K,
    long sA, long sW, long sC, float scale)
{
    const int bz = blockIdx.z;
    gemm_body<AM, OT>(A + (long)bz * sA, W + (long)bz * sW, C + (long)bz * sC,
                      lda, ldw, ldc, K, scale);
}

// dual GEMM (AM=8): z<4 -> scores batch z (y<8); z>=4 -> UT batch z-4 (y<4)
__global__ __launch_bounds__(256, 2) void gemm_dual(
    const u16* __restrict__ A0, const u16* __restrict__ W0, u16* __restrict__ C0,
    int lda0, int ldw0, int ldc0, long sA0, long sW0, long sC0, float scale0,
    const u16* __restrict__ A1, const u16* __restrict__ W1, u16* __restrict__ C1,
    int lda1, int ldw1, int ldc1, long sA1, long sW1, long sC1, float scale1)
{
    const int z = blockIdx.z;
    if (z < 4) {
        gemm_body<8, u16>(A0 + (long)z * sA0, W0 + (long)z * sW0, C0 + (long)z * sC0,
                          lda0, ldw0, ldc0, 1024, scale0);
    } else {
        if (blockIdx.y >= 4) return;   // uniform early-exit, before any barrier
        const int b = z - 4;
        gemm_body<8, u16>(A1 + (long)b * sA1, W1 + (long)b * sW1, C1 + (long)b * sC1,
                          lda1, ldw1, ldc1, 1024, scale1);
    }
}

// interleaved RoPE in-place on q and k: rows = b*2048+s, 512 pairs per row
__global__ __launch_bounds__(256) void rope_kernel(u16* q, u16* k) {
    const int row = blockIdx.x;
    const int pos = row & 2047;
    u16* p = (blockIdx.y ? k : q) + (long)row * 1024;
#pragma unroll
    for (int it = 0; it < 2; ++it) {
        const int i = threadIdx.x + it * 256;
        const float e = (float)i * (1.0f / 512.0f);
        const float inv = powf(10000.0f, -e);
        const float ang = (float)pos * inv;
        float s, c;
        sincosf(ang, &s, &c);
        const float xr = b2f(p[2 * i]);
        const float xi = b2f(p[2 * i + 1]);
        p[2 * i]     = f2b(xr * c - xi * s);
        p[2 * i + 1] = f2b(xr * s + xi * c);
    }
}

// row-wise softmax over 2048 bf16 entries, in-place safe; one block per row
__global__ __launch_bounds__(256) void softmax_kernel(const u16* __restrict__ S, u16* __restrict__ P) {
    const long row = blockIdx.x;
    const u16* src = S + row * 2048;
    u16* dst = P + row * 2048;
    const int t = threadIdx.x;
    const int lane = t & 63;
    const int wave = t >> 6;
    __shared__ float red[4];

    float v[8];
    const short8 raw = *(const short8*)&src[t * 8];
#pragma unroll
    for (int i = 0; i < 8; ++i) v[i] = b2f((u16)raw[i]);

    float m = v[0];
#pragma unroll
    for (int i = 1; i < 8; ++i) m = fmaxf(m, v[i]);
    for (int o = 32; o > 0; o >>= 1) m = fmaxf(m, __shfl_xor(m, o, 64));
    if (lane == 0) red[wave] = m;
    __syncthreads();
    m = fmaxf(fmaxf(red[0], red[1]), fmaxf(red[2], red[3]));
    __syncthreads();

    float sum = 0.f;
#pragma unroll
    for (int i = 0; i < 8; ++i) { v[i] = expf(v[i] - m); sum += v[i]; }
    for (int o = 32; o > 0; o >>= 1) sum += __shfl_xor(sum, o, 64);
    if (lane == 0) red[wave] = sum;
    __syncthreads();
    sum = red[0] + red[1] + red[2] + red[3];
    const float is = 1.0f / sum;

    short8 outv;
#pragma unroll
    for (int i = 0; i < 8; ++i) outv[i] = (short)f2b(v[i] * is);
    *(short8*)&dst[t * 8] = outv;
}

extern "C" void kernel_launch(void* const* d_in, const int* in_sizes, int n_in,
                              void* d_out, int out_size, void* d_ws, size_t ws_size,
                              hipStream_t stream)
{
    (void)in_sizes; (void)n_in; (void)out_size; (void)ws_size;
    const float* x  = (const float*)d_in[0];
    const float* wq = (const float*)d_in[1];
    const float* wk = (const float*)d_in[2];
    const float* wv = (const float*)d_in[3];
    const float* wo = (const float*)d_in[4];
    float* out = (float*)d_out;

    // workspace layout (bf16 elements), 104 MB total
    const long M1 = 1024 * 1024;
    u16* ws  = (u16*)d_ws;
    u16* xb  = ws;               // [8192][1024] bf16 x; reused as UT after QKV
    u16* wqb = xb + 8 * M1;      // [4][1024][1024] wq,wk,wv,wo contiguous
    u16* wob = wqb + 3 * M1;
    u16* q   = wqb + 4 * M1;     // [8192][1024]; kk, v contiguous after (z-strided)
    u16* kk  = q + 8 * M1;
    u16* v   = kk + 8 * M1;
    u16* sc  = v + 8 * M1;       // [4][2048][2048], softmax in-place
    u16* UT  = xb;               // alias: [4][1024][2048], xb dead after QKV

    const dim3 blk(256);

    // fp32 -> bf16 conversions (2 dispatches)
    cvt_f32_bf16<<<dim3(4096), blk, 0, stream>>>(x, xb, 8 * 1024 * 1024);
    cvt_weights<<<dim3(512, 1, 4), blk, 0, stream>>>(wq, wk, wv, wo, wqb);

    // QKV fused: z in {0,1,2} -> q, k, v   (M=8192, N=1024, K=1024; 256x128 tiles)
    gemm_bt<8, u16><<<dim3(8, 32, 3), blk, 0, stream>>>(xb, wqb, q,
        1024, 1024, 1024, 1024, 0, M1, 8 * M1, 1.0f);

    rope_kernel<<<dim3(8192, 2), blk, 0, stream>>>(q, kk);

    // fused (256x128 tiles): scores = q @ k^T / 32 (M=N=2048, z=0..3, y<8)
    //                      + UT[b] = wo @ v[b]^T (M=1024,N=2048, z=4..7, y<4)
    gemm_dual<<<dim3(16, 8, 8), blk, 0, stream>>>(
        q, kk, sc, 1024, 1024, 2048, 2 * M1, 2 * M1, 4 * M1, 0.03125f,
        wob, v, UT, 1024, 1024, 2048, 0, 2 * M1, 2 * M1, 1.0f);

    softmax_kernel<<<dim3(8192), blk, 0, stream>>>(sc, sc);

    // out[b] = P[b] @ UT[b]^T  (M=2048, N=1024, K=2048; 128x128 tiles), fp32 out
    gemm_bt<4, float><<<dim3(8, 16, 4), blk, 0, stream>>>(sc, UT, out,
        2048, 2048, 1024, 2048, 4 * M1, 2 * M1, 2 * M1, 1.0f);
}

// Round 7
// 326.577 us; speedup vs baseline: 1.0616x; 1.0616x over previous
//
#include <hip/hip_runtime.h>
#include <math.h>

typedef __attribute__((ext_vector_type(8))) short short8;
typedef __attribute__((ext_vector_type(4))) float f32x4;
typedef unsigned short u16;

__device__ __forceinline__ float b2f(u16 u) {
    union { unsigned u; float f; } c; c.u = ((unsigned)u) << 16; return c.f;
}
__device__ __forceinline__ u16 f2b(float f) {
    unsigned u = __float_as_uint(f);
    u += 0x7fffu + ((u >> 16) & 1u);   // RNE
    return (u16)(u >> 16);
}

__device__ __forceinline__ void gl_lds16(const u16* g, u16* l) {
    __builtin_amdgcn_global_load_lds(
        (const __attribute__((address_space(1))) void*)g,
        (__attribute__((address_space(3))) void*)l,
        16, 0, 0);
}

// fp32 -> bf16 (RNE), n multiple of 8, one thread per 8 elements
__global__ __launch_bounds__(256) void cvt_f32_bf16(const float* __restrict__ src,
                                                    u16* __restrict__ dst, int n) {
    const int i = (blockIdx.x * 256 + threadIdx.x) * 8;
    if (i >= n) return;
    const float4 a = *(const float4*)&src[i];
    const float4 b = *(const float4*)&src[i + 4];
    short8 o;
    o[0] = (short)f2b(a.x); o[1] = (short)f2b(a.y);
    o[2] = (short)f2b(a.z); o[3] = (short)f2b(a.w);
    o[4] = (short)f2b(b.x); o[5] = (short)f2b(b.y);
    o[6] = (short)f2b(b.z); o[7] = (short)f2b(b.w);
    *(short8*)&dst[i] = o;
}

// 4 weight matrices (1M fp32 each) -> contiguous bf16; z selects source
__global__ __launch_bounds__(256) void cvt_weights(
    const float* __restrict__ w0, const float* __restrict__ w1,
    const float* __restrict__ w2, const float* __restrict__ w3,
    u16* __restrict__ dst) {
    const int z = blockIdx.z;
    const float* src = (z == 0) ? w0 : (z == 1) ? w1 : (z == 2) ? w2 : w3;
    const int i = (blockIdx.x * 256 + threadIdx.x) * 8;
    const float4 a = *(const float4*)&src[i];
    const float4 b = *(const float4*)&src[i + 4];
    short8 o;
    o[0] = (short)f2b(a.x); o[1] = (short)f2b(a.y);
    o[2] = (short)f2b(a.z); o[3] = (short)f2b(a.w);
    o[4] = (short)f2b(b.x); o[5] = (short)f2b(b.y);
    o[6] = (short)f2b(b.z); o[7] = (short)f2b(b.w);
    *(short8*)&dst[(long)z * 1024 * 1024 + i] = o;
}

// Shared 128x128-tile GEMM body: C[M,N] = scale * A[M,K] @ W[N,K]^T
// bf16 in, fp32 accum. XOR-swizzled LDS (0 conflicts, verified R4);
// loop-carried pointers (R5). R7: DOUBLE-BUFFERED glds K-loop, ONE barrier
// per step — tile s+1 issued before computing tile s, so the vmcnt drain at
// the next barrier waits for loads issued a full compute-phase earlier.
template<typename OT>
__device__ __forceinline__ void gemm_body(
    const u16* __restrict__ A, const u16* __restrict__ W, OT* __restrict__ C,
    int lda, int ldw, int ldc, int K, float scale)
{
    __shared__ u16 lsA[2][128 * 32];
    __shared__ u16 lsB[2][128 * 32];

    const int m0 = blockIdx.y * 128;
    const int n0 = blockIdx.x * 128;
    const int t = threadIdx.x;
    const int lane = t & 63;
    const int wave = t >> 6;
    const int wm = (wave & 1) * 64;
    const int wn = (wave >> 1) * 64;

    // staging: thread t covers row sr; col-group XOR-swizzled by (t>>3)&3
    const int sr = t >> 2;
    const int scol = ((t & 3) ^ ((t >> 3) & 3)) * 8;

    // loop-carried global pointers (advance 32 elems = 64 B per K-step)
    const u16* pa0 = A + (long)(m0 + sr) * lda + scol;
    const u16* pa1 = pa0 + (long)64 * lda;
    const u16* pw0 = W + (long)(n0 + sr) * ldw + scol;
    const u16* pw1 = pw0 + (long)64 * ldw;

    f32x4 acc[4][4];
#pragma unroll
    for (int i = 0; i < 4; ++i)
#pragma unroll
        for (int j = 0; j < 4; ++j)
            acc[i][j] = (f32x4){0.f, 0.f, 0.f, 0.f};

    const int fr = lane & 15;   // fragment row (m / n)
    const int fq = lane >> 4;   // quad
    const int swz = (fq ^ ((fr >> 1) & 3)) * 8;
    const int aoff = (wm + fr) * 32 + swz;
    const int boff = (wn + fr) * 32 + swz;

    // prologue: tile 0 -> buffer 0
    gl_lds16(pa0, &lsA[0][t * 8]);        pa0 += 32;
    gl_lds16(pa1, &lsA[0][2048 + t * 8]); pa1 += 32;
    gl_lds16(pw0, &lsB[0][t * 8]);        pw0 += 32;
    gl_lds16(pw1, &lsB[0][2048 + t * 8]); pw1 += 32;

    const int nsteps = K >> 5;
    int par = 0;
    for (int s = 0; s < nsteps; ++s) {
        __syncthreads();   // drains vmcnt: buf[par] ready; prior ds_reads done
        if (s + 1 < nsteps) {
            const int np = par ^ 1;
            gl_lds16(pa0, &lsA[np][t * 8]);        pa0 += 32;
            gl_lds16(pa1, &lsA[np][2048 + t * 8]); pa1 += 32;
            gl_lds16(pw0, &lsB[np][t * 8]);        pw0 += 32;
            gl_lds16(pw1, &lsB[np][2048 + t * 8]); pw1 += 32;
        }

        short8 af[4], bf[4];
#pragma unroll
        for (int i = 0; i < 4; ++i)
            af[i] = *(const short8*)&lsA[par][aoff + i * 512];
#pragma unroll
        for (int j = 0; j < 4; ++j)
            bf[j] = *(const short8*)&lsB[par][boff + j * 512];
#pragma unroll
        for (int i = 0; i < 4; ++i)
#pragma unroll
            for (int j = 0; j < 4; ++j)
                acc[i][j] = __builtin_amdgcn_mfma_f32_16x16x32_bf16(af[i], bf[j], acc[i][j], 0, 0, 0);
        par ^= 1;
    }

    // C/D layout: col = lane&15, row = quad*4 + reg  [verified m89/m91]
#pragma unroll
    for (int i = 0; i < 4; ++i) {
#pragma unroll
        for (int j = 0; j < 4; ++j) {
            const int row0 = m0 + wm + i * 16 + fq * 4;
            const int col = n0 + wn + j * 16 + fr;
#pragma unroll
            for (int r = 0; r < 4; ++r) {
                const int row = row0 + r;
                const float val = acc[i][j][r] * scale;
                if (sizeof(OT) == 2) {
                    ((u16*)C)[(long)row * ldc + col] = f2b(val);
                } else {
                    ((float*)C)[(long)row * ldc + col] = val;
                }
            }
        }
    }
}

// generic z-strided GEMM
template<typename OT>
__global__ __launch_bounds__(256) void gemm_bt(
    const u16* __restrict__ A, const u16* __restrict__ W, OT* __restrict__ C,
    int lda, int ldw, int ldc, int K,
    long sA, long sW, long sC, float scale)
{
    const int bz = blockIdx.z;
    gemm_body<OT>(A + (long)bz * sA, W + (long)bz * sW, C + (long)bz * sC,
                  lda, ldw, ldc, K, scale);
}

// dual GEMM: z<4 -> scores batch z; z>=4 -> UT batch z-4 (only y<8 blocks)
__global__ __launch_bounds__(256) void gemm_dual(
    const u16* __restrict__ A0, const u16* __restrict__ W0, u16* __restrict__ C0,
    int lda0, int ldw0, int ldc0, long sA0, long sW0, long sC0, float scale0,
    const u16* __restrict__ A1, const u16* __restrict__ W1, u16* __restrict__ C1,
    int lda1, int ldw1, int ldc1, long sA1, long sW1, long sC1, float scale1)
{
    const int z = blockIdx.z;
    if (z < 4) {
        gemm_body<u16>(A0 + (long)z * sA0, W0 + (long)z * sW0, C0 + (long)z * sC0,
                       lda0, ldw0, ldc0, 1024, scale0);
    } else {
        if (blockIdx.y >= 8) return;   // uniform early-exit, before any barrier
        const int b = z - 4;
        gemm_body<u16>(A1 + (long)b * sA1, W1 + (long)b * sW1, C1 + (long)b * sC1,
                       lda1, ldw1, ldc1, 1024, scale1);
    }
}

// interleaved RoPE in-place on q and k: rows = b*2048+s, 512 pairs per row
__global__ __launch_bounds__(256) void rope_kernel(u16* q, u16* k) {
    const int row = blockIdx.x;
    const int pos = row & 2047;
    u16* p = (blockIdx.y ? k : q) + (long)row * 1024;
#pragma unroll
    for (int it = 0; it < 2; ++it) {
        const int i = threadIdx.x + it * 256;
        const float e = (float)i * (1.0f / 512.0f);
        const float inv = powf(10000.0f, -e);
        const float ang = (float)pos * inv;
        float s, c;
        sincosf(ang, &s, &c);
        const float xr = b2f(p[2 * i]);
        const float xi = b2f(p[2 * i + 1]);
        p[2 * i]     = f2b(xr * c - xi * s);
        p[2 * i + 1] = f2b(xr * s + xi * c);
    }
}

// row-wise softmax over 2048 bf16 entries, in-place safe; one block per row
__global__ __launch_bounds__(256) void softmax_kernel(const u16* __restrict__ S, u16* __restrict__ P) {
    const long row = blockIdx.x;
    const u16* src = S + row * 2048;
    u16* dst = P + row * 2048;
    const int t = threadIdx.x;
    const int lane = t & 63;
    const int wave = t >> 6;
    __shared__ float red[4];

    float v[8];
    const short8 raw = *(const short8*)&src[t * 8];
#pragma unroll
    for (int i = 0; i < 8; ++i) v[i] = b2f((u16)raw[i]);

    float m = v[0];
#pragma unroll
    for (int i = 1; i < 8; ++i) m = fmaxf(m, v[i]);
    for (int o = 32; o > 0; o >>= 1) m = fmaxf(m, __shfl_xor(m, o, 64));
    if (lane == 0) red[wave] = m;
    __syncthreads();
    m = fmaxf(fmaxf(red[0], red[1]), fmaxf(red[2], red[3]));
    __syncthreads();

    float sum = 0.f;
#pragma unroll
    for (int i = 0; i < 8; ++i) { v[i] = expf(v[i] - m); sum += v[i]; }
    for (int o = 32; o > 0; o >>= 1) sum += __shfl_xor(sum, o, 64);
    if (lane == 0) red[wave] = sum;
    __syncthreads();
    sum = red[0] + red[1] + red[2] + red[3];
    const float is = 1.0f / sum;

    short8 outv;
#pragma unroll
    for (int i = 0; i < 8; ++i) outv[i] = (short)f2b(v[i] * is);
    *(short8*)&dst[t * 8] = outv;
}

extern "C" void kernel_launch(void* const* d_in, const int* in_sizes, int n_in,
                              void* d_out, int out_size, void* d_ws, size_t ws_size,
                              hipStream_t stream)
{
    (void)in_sizes; (void)n_in; (void)out_size; (void)ws_size;
    const float* x  = (const float*)d_in[0];
    const float* wq = (const float*)d_in[1];
    const float* wk = (const float*)d_in[2];
    const float* wv = (const float*)d_in[3];
    const float* wo = (const float*)d_in[4];
    float* out = (float*)d_out;

    // workspace layout (bf16 elements), 104 MB total
    const long M1 = 1024 * 1024;
    u16* ws  = (u16*)d_ws;
    u16* xb  = ws;               // [8192][1024] bf16 x; reused as UT after QKV
    u16* wqb = xb + 8 * M1;      // [4][1024][1024] wq,wk,wv,wo contiguous
    u16* wob = wqb + 3 * M1;
    u16* q   = wqb + 4 * M1;     // [8192][1024]; kk, v contiguous after (z-strided)
    u16* kk  = q + 8 * M1;
    u16* v   = kk + 8 * M1;
    u16* sc  = v + 8 * M1;       // [4][2048][2048], softmax in-place
    u16* UT  = xb;               // alias: [4][1024][2048], xb dead after QKV

    const dim3 blk(256);

    // fp32 -> bf16 conversions (2 dispatches)
    cvt_f32_bf16<<<dim3(4096), blk, 0, stream>>>(x, xb, 8 * 1024 * 1024);
    cvt_weights<<<dim3(512, 1, 4), blk, 0, stream>>>(wq, wk, wv, wo, wqb);

    // QKV fused: z in {0,1,2} -> q, k, v   (M=8192, N=1024, K=1024)
    gemm_bt<u16><<<dim3(8, 64, 3), blk, 0, stream>>>(xb, wqb, q,
        1024, 1024, 1024, 1024, 0, M1, 8 * M1, 1.0f);

    rope_kernel<<<dim3(8192, 2), blk, 0, stream>>>(q, kk);

    // fused: scores = q @ k^T / 32 (M=N=2048,K=1024, z=0..3)
    //      + UT[b][e][k] = wo @ v[b]^T (M=1024,N=2048,K=1024, z=4..7, y<8)
    gemm_dual<<<dim3(16, 16, 8), blk, 0, stream>>>(
        q, kk, sc, 1024, 1024, 2048, 2 * M1, 2 * M1, 4 * M1, 0.03125f,
        wob, v, UT, 1024, 1024, 2048, 0, 2 * M1, 2 * M1, 1.0f);

    softmax_kernel<<<dim3(8192), blk, 0, stream>>>(sc, sc);

    // out[b] = P[b] @ UT[b]^T   (M=2048, N=1024, K=2048), fp32 output
    gemm_bt<float><<<dim3(8, 16, 4), blk, 0, stream>>>(sc, UT, out,
        2048, 2048, 1024, 2048, 4 * M1, 2 * M1, 2 * M1, 1.0f);
}